// Round 1
// baseline (149.917 us; speedup 1.0000x reference)
//
#include <hip/hip_runtime.h>

namespace {

constexpr int B = 16;
constexpr int C = 1024;
constexpr int BC = B * C;                          // 16384
constexpr long long BCC = (long long)B * C * C;    // 16777216
constexpr float EPS  = 1e-12f;
constexpr float TINY = 1e-9f;

// One workgroup per output row (b, i). 256 threads x 4 j-elements each.
// Single pass: per-element relaxations -> 6 block reductions -> row scalars
// -> scaled coef writes (a_u/a_l held in registers across the reduction).
__global__ __launch_bounds__(256) void bounded_softmax_kernel(
    const float* __restrict__ lower,
    const float* __restrict__ upper,
    float* __restrict__ out)
{
    const int row = blockIdx.x;            // row = b*C + i
    const int b   = row >> 10;             // C == 1024
    const int i   = row & (C - 1);
    const int tid = threadIdx.x;

    const float* __restrict__ lrow = lower + b * C;
    const float* __restrict__ urow = upper + b * C;

    const float l_i = lrow[i];
    const float u_i = urow[i];

    const float4 lj4 = *reinterpret_cast<const float4*>(lrow + tid * 4);
    const float4 uj4 = *reinterpret_cast<const float4*>(urow + tid * 4);
    const float ljv[4] = {lj4.x, lj4.y, lj4.z, lj4.w};
    const float ujv[4] = {uj4.x, uj4.y, uj4.z, uj4.w};

    float a_u[4], a_l[4];
    // acc: S_l, S_u, sum_a_u, sum_a_l, sum_b_u, sum_b_l
    float acc[6] = {0.f, 0.f, 0.f, 0.f, 0.f, 0.f};

    #pragma unroll
    for (int k = 0; k < 4; ++k) {
        const int j = tid * 4 + k;
        const float l_d = ljv[k] - u_i;      // lower bound of x_j - x_i
        const float u_d = ujv[k] - l_i;      // upper bound
        const float el  = __expf(l_d);
        const float eu  = __expf(u_d);
        const float denom = u_d - l_d;       // >= 0
        float au = (eu - el) / (denom + EPS);
        au = (fabsf(denom) < TINY) ? eu : au;
        const float bu = fmaf(-au, l_d, el); // exp_l - a_u * l_d
        const float t  = 0.5f * (l_d + u_d);
        const float al = __expf(t);
        const float bl = al * (1.0f - t);    // a_l - a_l * t

        float elz = el, euz = eu, auz = au, buz = bu, alz = al, blz = bl;
        if (j == i) { elz = euz = auz = buz = alz = blz = 0.0f; }

        acc[0] += elz; acc[1] += euz; acc[2] += auz;
        acc[3] += alz; acc[4] += buz; acc[5] += blz;
        a_u[k] = auz; a_l[k] = alz;
    }

    // Block reduction: per-wave shuffle tree, then 4 wave-partials via LDS.
    __shared__ float red[4][6];
    const int lane = tid & 63;
    const int wid  = tid >> 6;
    #pragma unroll
    for (int m = 0; m < 6; ++m) {
        float v = acc[m];
        #pragma unroll
        for (int o = 32; o > 0; o >>= 1) v += __shfl_down(v, o);
        if (lane == 0) red[wid][m] = v;
    }
    __syncthreads();

    const float S_l  = red[0][0] + red[1][0] + red[2][0] + red[3][0];
    const float S_u  = red[0][1] + red[1][1] + red[2][1] + red[3][1];
    const float SA_u = red[0][2] + red[1][2] + red[2][2] + red[3][2];
    const float SA_l = red[0][3] + red[1][3] + red[2][3] + red[3][3];
    const float SB_u = red[0][4] + red[1][4] + red[2][4] + red[3][4];
    const float SB_l = red[0][5] + red[1][5] + red[2][5] + red[3][5];

    // g(S) = 1/(1+S) relaxations
    const float g_l = 1.0f / (1.0f + S_l);
    const float g_u = 1.0f / (1.0f + S_u);
    const float dg  = S_u - S_l;             // >= 0
    float m_u = (g_u - g_l) / (dg + EPS);
    m_u = (fabsf(dg) < TINY) ? (-g_u * g_u) : m_u;
    const float c_u = g_l - m_u * S_l;
    const float m_l = -g_u * g_u;
    const float c_l = g_u - m_l * S_u;

    // Big (B,C,C) coef outputs: coef = m * (a - eye*sum_a)
    float* __restrict__ lower_coef = out + 2 * BC + (long long)row * C;
    float* __restrict__ upper_coef = out + 2 * BC + BCC + (long long)row * C;

    float lv[4], uv[4];
    #pragma unroll
    for (int k = 0; k < 4; ++k) {
        const int j = tid * 4 + k;
        const float dl = (j == i) ? SA_l : 0.0f;
        const float du = (j == i) ? SA_u : 0.0f;
        lv[k] = m_l * (a_l[k] - dl);
        uv[k] = m_u * (a_u[k] - du);
    }
    *reinterpret_cast<float4*>(lower_coef + tid * 4) =
        make_float4(lv[0], lv[1], lv[2], lv[3]);
    *reinterpret_cast<float4*>(upper_coef + tid * 4) =
        make_float4(uv[0], uv[1], uv[2], uv[3]);

    if (tid == 0) {
        const float soft_lower = fminf(fmaxf(g_u, 0.0f), 1.0f);
        const float soft_upper = fminf(fmaxf(g_l, 0.0f), 1.0f);
        out[row]                          = soft_lower;
        out[BC + row]                     = soft_upper;
        out[2 * BC + 2 * BCC + row]       = fmaf(m_l, SB_l, c_l);  // final_lower_bias
        out[2 * BC + 2 * BCC + BC + row]  = fmaf(m_u, SB_u, c_u);  // final_upper_bias
    }
}

} // namespace

extern "C" void kernel_launch(void* const* d_in, const int* in_sizes, int n_in,
                              void* d_out, int out_size, void* d_ws, size_t ws_size,
                              hipStream_t stream) {
    const float* lower = (const float*)d_in[0];
    const float* upper = (const float*)d_in[1];
    float* out = (float*)d_out;
    bounded_softmax_kernel<<<dim3(B * C), dim3(256), 0, stream>>>(lower, upper, out);
}